// Round 12
// baseline (402.115 us; speedup 1.0000x reference)
//
#include <hip/hip_runtime.h>
#include <math.h>

typedef _Float16 f16;
typedef _Float16 f16x4 __attribute__((ext_vector_type(4)));
typedef _Float16 f16x8 __attribute__((ext_vector_type(8)));
typedef float f32x4 __attribute__((ext_vector_type(4)));
typedef float f32x16 __attribute__((ext_vector_type(16)));

// ---------------------------------------------------------------------------
// Repack weights (96, V, K) fp32 -> wpack[t][ch][VP] f16, zero-padded v >= V.
// ---------------------------------------------------------------------------
template<int V, int K, int VP>
__global__ void repack_kernel(const float* __restrict__ w, f16* __restrict__ wp) {
    int i = blockIdx.x * 256 + threadIdx.x;
    if (i >= K * 96 * VP) return;
    int v = i % VP, ch = (i / VP) % 96, t = i / (VP * 96);
    float val = (v < V) ? w[(ch * V + v) * K + t] : 0.f;
    wp[i] = (f16)val;
}

// ---------------------------------------------------------------------------
// PROTEIN + Gram/readout fused. 16x16x32 f16 MFMA, r10 numerics.
// Changes vs r10 (from its counters: phases serialize, 1.9x over DS demand):
//  * 512 threads, 1 block/CU: weights in LDS ONCE (49KB not 2x), chunks of
//    512 rows double-buffered (2x41.6KB) -> stage(c+1) and compute(c) share
//    one region, ONE barrier per chunk; 8-wave drift overlaps VMEM w/ MFMA.
//  * staging: unit = 8 vocab x 4 pos: 8 COALESCED float4 loads + register
//    transpose + 4 x ds_write_b128 (4.4x fewer DS writes than r10 b32s).
//  * swizzle ((row>>3)^(row>>5))&3: write collisions only rows 128 apart
//    (2-way = free, m136). Reads use the same XOR.
//  * transients only (r3/r4/r5/r9 lesson: no fat arrays across barriers);
//    acc folds to runmax before each barrier.
//  * epilogue: bias+relu+maxpool -> gram(6x32) -> L2-normalize -> dot, out[b].
// ---------------------------------------------------------------------------
__global__ __launch_bounds__(512, 1) void conv_pro_fused_kernel(
    const float* __restrict__ in,        // (B, 25, 1000) f32
    const f16*   __restrict__ wp,        // (8, 96, 32) f16
    const float* __restrict__ bias,      // (96) = b_pro
    const float* __restrict__ feat_lig,  // (B, 192): cols 0..95 from ligand
    const float* __restrict__ w_aff,     // (1024)
    const float* __restrict__ b_aff,     // (1)
    float* __restrict__ out)             // (B)
{
    constexpr int V = 25, L = 1000, KT = 8, LOUT = 993;
    constexpr int CH  = 512;           // output rows per chunk
    constexpr int NC  = 2;             // chunks (2*512 >= 993+7)
    constexpr int BR  = 520;           // buffer rows (512 + 7 halo, pad 520)
    constexpr int RSB = 80;            // row stride bytes (64 payload + 16)
    constexpr int P4  = BR / 4;        // 130 position-quads
    constexpr int NU  = 4 * P4;        // 520 staging units (4 vocab-octs)
    constexpr int NW  = KT * 96 * 32;  // 24576 f16 weights (49152 B)

    __shared__ __align__(16) char s_buf[2][BR * RSB];  // 83.2 KB
    __shared__ __align__(16) f16  s_w[NW];             // 49.2 KB
    __shared__ float s_red[8 * 96];                    // 3 KB
    __shared__ float s_x[192];
    // total ~136.2 KB -> 1 block/CU

    const int tid  = threadIdx.x;
    const int wave = tid >> 6;
    const int lane = tid & 63;
    const int g    = lane >> 4;        // k-oct (0..3)
    const int r16  = lane & 15;        // A-row / B-col within 16-tile
    const size_t b = blockIdx.x;
    const float* gs = in + b * (size_t)(V * L);

    auto SWZ = [](int row) { return (((row >> 3) ^ (row >> 5)) & 3) << 4; };

    // ---- staging: coalesced loads, register transpose, b128 writes ----
    auto stage = [&](int c, char* sb) {
        const int base = c * CH;
        for (int i = tid; i < NU; i += 512) {
            const int vg = i / P4, p4 = i - vg * P4;
            const int p = 4 * p4, gp = base + p;
            float x[8][4];
            #pragma unroll
            for (int vv = 0; vv < 8; ++vv) {
                const int v = vg * 8 + vv;
                float4 t4 = {0.f, 0.f, 0.f, 0.f};
                if (gp < L && v < V)
                    t4 = *(const float4*)(gs + (size_t)v * L + gp);
                x[vv][0] = t4.x; x[vv][1] = t4.y; x[vv][2] = t4.z; x[vv][3] = t4.w;
            }
            #pragma unroll
            for (int j = 0; j < 4; ++j) {
                const int row = p + j;
                f16x8 hv;
                #pragma unroll
                for (int vv = 0; vv < 8; ++vv) hv[vv] = (f16)x[vv][j];
                *(f16x8*)(sb + row * RSB + ((vg * 16) ^ SWZ(row))) = hv;
            }
        }
    };

    float runmax[6];
    #pragma unroll
    for (int c6 = 0; c6 < 6; ++c6) runmax[c6] = -3.0e38f;

    // ---- compute one chunk from sb; fold into runmax ----
    auto compute = [&](int c, const char* sb) {
        f32x4 acc[4][6] = {};
        #pragma unroll 1
        for (int t = 0; t < KT; ++t) {
            f16x8 bf[6];
            #pragma unroll
            for (int c6 = 0; c6 < 6; ++c6)
                bf[c6] = *(const f16x8*)(s_w + (t * 96 + c6 * 16 + r16) * 32 + g * 8);
            #pragma unroll
            for (int tt = 0; tt < 4; ++tt) {
                const int row = (wave * 4 + tt) * 16 + r16 + t;   // <= 518 < BR
                f16x8 a = *(const f16x8*)(sb + row * RSB + ((g * 16) ^ SWZ(row)));
                #pragma unroll
                for (int c6 = 0; c6 < 6; ++c6)
                    acc[tt][c6] = __builtin_amdgcn_mfma_f32_16x16x32_f16(a, bf[c6], acc[tt][c6], 0, 0, 0);
            }
        }
        #pragma unroll
        for (int tt = 0; tt < 4; ++tt) {
            const int pt = c * CH + (wave * 4 + tt) * 16;
            if (pt + 16 <= LOUT) {
                #pragma unroll
                for (int c6 = 0; c6 < 6; ++c6)
                    #pragma unroll
                    for (int i = 0; i < 4; ++i)
                        runmax[c6] = fmaxf(runmax[c6], acc[tt][c6][i]);
            } else {
                const int p0g = pt + g * 4;   // C/D: col=lane&15, row=g*4+i
                #pragma unroll
                for (int c6 = 0; c6 < 6; ++c6)
                    #pragma unroll
                    for (int i = 0; i < 4; ++i)
                        if (p0g + i < LOUT) runmax[c6] = fmaxf(runmax[c6], acc[tt][c6][i]);
            }
        }
    };

    // ---- weights -> LDS + prologue stage ----
    {
        const f16x8* wg = (const f16x8*)wp;
        f16x8* wl = (f16x8*)s_w;
        #pragma unroll
        for (int u = 0; u < NW / 8 / 512; ++u)   // 6 iters
            wl[u * 512 + tid] = wg[u * 512 + tid];
    }
    stage(0, s_buf[0]);
    __syncthreads();

    // ---- chunk 0: stage(1) overlaps compute(0) via wave drift ----
    stage(1, s_buf[1]);
    compute(0, s_buf[0]);
    __syncthreads();
    compute(1, s_buf[1]);

    // ---- reduce maxpool: lanes {r16, +16, +32, +48} hold channel c6*16+r16 ----
    #pragma unroll
    for (int c6 = 0; c6 < 6; ++c6) {
        runmax[c6] = fmaxf(runmax[c6], __shfl_xor(runmax[c6], 16, 64));
        runmax[c6] = fmaxf(runmax[c6], __shfl_xor(runmax[c6], 32, 64));
    }
    if (lane < 16) {
        #pragma unroll
        for (int c6 = 0; c6 < 6; ++c6)
            s_red[wave * 96 + c6 * 16 + lane] = runmax[c6];
    }
    __syncthreads();

    // ---- combine waves, bias+relu; assemble x = [lig(96), pro(96)] ----
    if (tid < 96) {
        float m = s_red[tid];
        #pragma unroll
        for (int w = 1; w < 8; ++w) m = fmaxf(m, s_red[w * 96 + tid]);
        s_x[96 + tid] = fmaxf(m + bias[tid], 0.f);
        s_x[tid] = feat_lig[b * 192 + tid];       // ligand half (already relu'd)
    }
    __syncthreads();

    // ---- gram (6,32) -> normalize -> dot: 1024 jk over 512 threads ----
    float ssum = 0.f, sdot = 0.f;
    #pragma unroll
    for (int u = 0; u < 2; ++u) {
        const int jk = u * 512 + tid;
        const int j = jk >> 5, k = jk & 31;
        float gg = 0.f;
        #pragma unroll
        for (int i = 0; i < 6; ++i)
            gg = fmaf(s_x[i * 32 + j], s_x[i * 32 + k], gg);
        ssum = fmaf(gg, gg, ssum);
        sdot = fmaf(gg, w_aff[jk], sdot);
    }
    #pragma unroll
    for (int off = 32; off >= 1; off >>= 1) {
        ssum += __shfl_xor(ssum, off, 64);
        sdot += __shfl_xor(sdot, off, 64);
    }
    if (lane == 0) { s_red[wave] = ssum; s_red[8 + wave] = sdot; }
    __syncthreads();
    if (tid == 0) {
        float S = 0.f, D = 0.f;
        #pragma unroll
        for (int w = 0; w < 8; ++w) { S += s_red[w]; D += s_red[8 + w]; }
        out[b] = D / (sqrtf(S) + 1e-12f) + b_aff[0];
    }
}

// ---------------------------------------------------------------------------
// LIGAND branch: round-2 kernel (proven; ~25 us). Writes feat[:, 0:96].
// ---------------------------------------------------------------------------
__global__ __launch_bounds__(384) void conv_lig_kernel(
    const float* __restrict__ in,    // (B, 64, 100) f32
    const f16*   __restrict__ wp,    // (4, 96, 64) f16
    const float* __restrict__ bias,  // (96)
    float* __restrict__ feat,        // (B, 192)
    int feat_off)
{
    constexpr int V = 64, L = 100, KT = 4, VP = 64, KSTEPS = 4;
    constexpr int LP = 132, RS = 72, NTILES = 4, LOUT = 97;
    constexpr int RSB = RS * 2, NQ = V / 4;
    __shared__ __align__(16) char s_raw[LP * RSB];

    const int tid  = threadIdx.x;
    const int b    = blockIdx.x;
    const int wave = tid >> 6;
    const int lane = tid & 63;
    const int colw = wave % 3;
    const int roww = wave / 3;
    const int q    = lane >> 5;
    const int r    = lane & 31;

    {   // zero LDS (covers row pad)
        float4 z = {0.f, 0.f, 0.f, 0.f};
        float4* sz = (float4*)s_raw;
        for (int i = tid; i < LP * RSB / 16; i += 384) sz[i] = z;
    }
    __syncthreads();

    const float* gin = in + (size_t)b * (V * L);
    for (int i = tid; i < NQ * L; i += 384) {
        int q4 = i / L, p = i - q4 * L;
        const float* gp = gin + q4 * 4 * L + p;
        f16x4 hv = { (f16)gp[0], (f16)gp[L], (f16)gp[2 * L], (f16)gp[3 * L] };
        int off = (8 * q4) ^ (((p >> 3) & 3) << 4);
        *(f16x4*)(s_raw + p * RSB + off) = hv;
    }

    f16x8 bfr[KT][KSTEPS];
    #pragma unroll
    for (int t = 0; t < KT; ++t)
        #pragma unroll
        for (int ks = 0; ks < KSTEPS; ++ks)
            bfr[t][ks] = *(const f16x8*)(wp + (t * 96 + colw * 32 + r) * VP + ks * 16 + q * 8);

    __syncthreads();

    float runmax = -3.0e38f;
    for (int it = 0; it < NTILES / 2; ++it) {
        const int p0 = (roww * (NTILES / 2) + it) * 32;
        f32x16 acc = {};
        #pragma unroll
        for (int t = 0; t < KT; ++t) {
            int row = p0 + r + t;
            if (row > LP - 1) row = LP - 1;          // clamped row is zero
            const char* ap = s_raw + row * RSB;
            const int swz = ((row >> 3) & 3) << 4;
            #pragma unroll
            for (int ks = 0; ks < KSTEPS; ++ks) {
                f16x8 af = *(const f16x8*)(ap + ((ks * 32 + q * 16) ^ swz));
                acc = __builtin_amdgcn_mfma_f32_32x32x16_f16(af, bfr[t][ks], acc, 0, 0, 0);
            }
        }
        #pragma unroll
        for (int i = 0; i < 16; ++i) {
            int rr = (i & 3) + 8 * (i >> 2) + 4 * q;
            if (p0 + rr < LOUT) runmax = fmaxf(runmax, acc[i]);
        }
    }
    runmax = fmaxf(runmax, __shfl_xor(runmax, 32, 64));

    __syncthreads();
    float* s_red = (float*)s_raw;     // [2][96]
    if (lane < 32) s_red[roww * 96 + colw * 32 + r] = runmax;
    __syncthreads();
    if (tid < 96) {
        float m = fmaxf(s_red[tid], s_red[96 + tid]);
        feat[(size_t)b * 192 + feat_off + tid] = fmaxf(m + bias[tid], 0.f);
    }
}

extern "C" void kernel_launch(void* const* d_in, const int* in_sizes, int n_in,
                              void* d_out, int out_size, void* d_ws, size_t ws_size,
                              hipStream_t stream)
{
    const float* protein = (const float*)d_in[0];  // (B, 25, 1000)
    const float* ligand  = (const float*)d_in[1];  // (B, 64, 100)
    const float* w_pro   = (const float*)d_in[2];  // (96, 25, 8)
    const float* b_pro   = (const float*)d_in[3];  // (96,)
    const float* w_lig   = (const float*)d_in[4];  // (96, 64, 4)
    const float* b_lig   = (const float*)d_in[5];  // (96,)
    const float* w_aff   = (const float*)d_in[6];  // (1024,)
    const float* b_aff   = (const float*)d_in[7];  // (1,)
    float* out = (float*)d_out;
    const int B = out_size;                        // 4096

    float* feat   = (float*)d_ws;                              // (B,192) f32
    f16*   wpackP = (f16*)((char*)d_ws + (size_t)B * 192 * 4); // 8*96*32 f16
    f16*   wpackL = wpackP + 8 * 96 * 32;                      // 4*96*64 f16

    repack_kernel<25, 8, 32><<<96, 256, 0, stream>>>(w_pro, wpackP);
    repack_kernel<64, 4, 64><<<96, 256, 0, stream>>>(w_lig, wpackL);

    // ligand branch -> feat[:, 0:96]
    conv_lig_kernel<<<B, 384, 0, stream>>>(ligand, wpackL, b_lig, feat, 0);
    // protein branch + gram + normalize + readout (fused) -> out
    conv_pro_fused_kernel<<<B, 512, 0, stream>>>(
        protein, wpackP, b_pro, feat, w_aff, b_aff, out);
}

// Round 13
// 359.153 us; speedup vs baseline: 1.1196x; 1.1196x over previous
//
#include <hip/hip_runtime.h>
#include <math.h>

typedef _Float16 f16;
typedef _Float16 f16x4 __attribute__((ext_vector_type(4)));
typedef _Float16 f16x8 __attribute__((ext_vector_type(8)));
typedef float f32x4 __attribute__((ext_vector_type(4)));
typedef float f32x16 __attribute__((ext_vector_type(16)));

// ---------------------------------------------------------------------------
// Ligand repack: (96, V, K) fp32 -> wp[t][ch][VP] f16 (round-2 layout).
// ---------------------------------------------------------------------------
template<int V, int K, int VP>
__global__ void repack_kernel(const float* __restrict__ w, f16* __restrict__ wp) {
    int i = blockIdx.x * 256 + threadIdx.x;
    if (i >= K * 96 * VP) return;
    int v = i % VP, ch = (i / VP) % 96, t = i / (VP * 96);
    float val = (v < V) ? w[(ch * V + v) * K + t] : 0.f;
    wp[i] = (f16)val;
}

// ---------------------------------------------------------------------------
// Protein repack: CONFLICT-FREE B layout. wp2 element index:
//   idx = ((t*6 + c6)*64 + lane)*8 + e, lane = g*16+r16, ch = c6*16+r16,
//   v = g*8+e. Lane l's 16B B-fragment is at byte ((t*6+c6)*64+l)*16 ->
//   16-lane phases read 256B contiguous = all 32 banks x2 = conflict-free.
// ---------------------------------------------------------------------------
__global__ void repack_pro_kernel(const float* __restrict__ w, f16* __restrict__ wp) {
    constexpr int V = 25, K = 8;
    int i = blockIdx.x * 256 + threadIdx.x;     // [0, 8*6*64*8)
    if (i >= K * 6 * 64 * 8) return;
    int e = i & 7, l = (i >> 3) & 63, c6 = (i >> 9) % 6, t = i / (512 * 6);
    int r16 = l & 15, g = l >> 4;
    int ch = c6 * 16 + r16, v = g * 8 + e;
    float val = (v < V) ? w[(ch * V + v) * K + t] : 0.f;
    wp[i] = (f16)val;
}

// ---------------------------------------------------------------------------
// PROTEIN. r10 skeleton (256 thr, 2 blocks/CU, CH=256 chunks, LDS weights;
// proven 243us) + two fixes from r12's counter evidence:
//  1. B-reads via conflict-free [t][c6][lane] layout (was 8-way on every
//     B-read -- the real source of the 2.5-3e7 conflict counter).
//  2. r12-style staging: 8 coalesced float4 loads + reg transpose + 4x
//     ds_write_b128 (4.4x fewer DS writes), full payload written -> no
//     pad-zero pass. Swizzle ((row>>3)^(row>>5))&3 on 16B slots.
// Transients only (no fat arrays across barriers); acc in accumulators.
// ---------------------------------------------------------------------------
__global__ __launch_bounds__(256, 2) void conv_pro_kernel(
    const float* __restrict__ in,    // (B, 25, 1000) f32
    const f16*   __restrict__ wp,    // conflict-free layout, 49152 B
    const float* __restrict__ bias,  // (96)
    float* __restrict__ feat,        // (B, 192)
    int feat_off)
{
    constexpr int V = 25, L = 1000, KT = 8, LOUT = 993;
    constexpr int CH  = 256;          // output rows per chunk
    constexpr int NC  = 4;            // chunks
    constexpr int BR  = 264;          // buffer rows (256 + 7 halo, pad 264)
    constexpr int RSB = 80;           // row stride bytes (64 payload + 16 pad)
    constexpr int P4  = BR / 4;       // 66 position-quads
    constexpr int NU  = 4 * P4;       // 264 staging units (4 vocab-octs)
    constexpr int NW  = KT * 6 * 64 * 8;  // 24576 f16 (49152 B)

    __shared__ __align__(16) char s_raw[BR * RSB];   // 21.1 KB
    __shared__ __align__(16) f16  s_w[NW];           // 49.2 KB
    __shared__ float s_red[4 * 96];

    const int tid  = threadIdx.x;
    const int wave = tid >> 6;
    const int lane = tid & 63;
    const int g    = lane >> 4;       // k-oct (0..3)
    const int r16  = lane & 15;       // A-row / B-col within 16-tile
    const size_t b = blockIdx.x;
    const float* gs = in + b * (size_t)(V * L);

    auto SWZ = [](int row) { return (((row >> 3) ^ (row >> 5)) & 3) << 4; };

    // ---- one-time: weights -> LDS (linear copy; layout pre-permuted) ----
    {
        const f16x8* wg = (const f16x8*)wp;
        f16x8* wl = (f16x8*)s_w;
        #pragma unroll
        for (int u = 0; u < NW / 8 / 256; ++u)       // 12 iters
            wl[u * 256 + tid] = wg[u * 256 + tid];
    }
    __syncthreads();

    float runmax[6];
    #pragma unroll
    for (int c6 = 0; c6 < 6; ++c6) runmax[c6] = -3.0e38f;

    for (int c = 0; c < NC; ++c) {
        if (c) __syncthreads();       // previous chunk's compute done
        // ---- stage chunk c: 8 coalesced float4 loads + transpose + b128 ----
        #pragma unroll
        for (int u = 0; u < 2; ++u) {
            const int i = u * 256 + tid;
            if (i < NU) {
                const int vg = i / P4, p4 = i - vg * P4;
                const int p = 4 * p4, gp = c * CH + p;
                float x[8][4];
                #pragma unroll
                for (int vv = 0; vv < 8; ++vv) {
                    const int v = vg * 8 + vv;
                    float4 t4 = {0.f, 0.f, 0.f, 0.f};
                    if (gp < L && v < V)
                        t4 = *(const float4*)(gs + (size_t)v * L + gp);
                    x[vv][0] = t4.x; x[vv][1] = t4.y; x[vv][2] = t4.z; x[vv][3] = t4.w;
                }
                #pragma unroll
                for (int j = 0; j < 4; ++j) {
                    const int row = p + j;
                    f16x8 hv;
                    #pragma unroll
                    for (int vv = 0; vv < 8; ++vv) hv[vv] = (f16)x[vv][j];
                    *(f16x8*)(s_raw + row * RSB + ((vg * 16) ^ SWZ(row))) = hv;
                }
            }
        }
        __syncthreads();              // staging visible

        // ---- compute: wave owns 4 row-tiles; B-reads conflict-free ----
        f32x4 acc[4][6] = {};
        #pragma unroll 1
        for (int t = 0; t < KT; ++t) {
            f16x8 bf[6];
            #pragma unroll
            for (int c6 = 0; c6 < 6; ++c6)
                bf[c6] = *(const f16x8*)(s_w + ((t * 6 + c6) * 64 + lane) * 8);
            #pragma unroll
            for (int tt = 0; tt < 4; ++tt) {
                const int row = (wave * 4 + tt) * 16 + r16 + t;   // <= 262 < BR
                f16x8 a = *(const f16x8*)(s_raw + row * RSB + ((g * 16) ^ SWZ(row)));
                #pragma unroll
                for (int c6 = 0; c6 < 6; ++c6)
                    acc[tt][c6] = __builtin_amdgcn_mfma_f32_16x16x32_f16(a, bf[c6], acc[tt][c6], 0, 0, 0);
            }
        }
        // ---- fold acc into runmax; C/D: col=lane&15, row=g*4+i ----
        #pragma unroll
        for (int tt = 0; tt < 4; ++tt) {
            const int pt = c * CH + (wave * 4 + tt) * 16;
            if (pt + 16 <= LOUT) {
                #pragma unroll
                for (int c6 = 0; c6 < 6; ++c6)
                    #pragma unroll
                    for (int i = 0; i < 4; ++i)
                        runmax[c6] = fmaxf(runmax[c6], acc[tt][c6][i]);
            } else {
                const int p0g = pt + g * 4;
                #pragma unroll
                for (int c6 = 0; c6 < 6; ++c6)
                    #pragma unroll
                    for (int i = 0; i < 4; ++i)
                        if (p0g + i < LOUT) runmax[c6] = fmaxf(runmax[c6], acc[tt][c6][i]);
            }
        }
    }

    // ---- reduce: channel c6*16+r16 held by g-groups {r16, +16, +32, +48} ----
    #pragma unroll
    for (int c6 = 0; c6 < 6; ++c6) {
        runmax[c6] = fmaxf(runmax[c6], __shfl_xor(runmax[c6], 16, 64));
        runmax[c6] = fmaxf(runmax[c6], __shfl_xor(runmax[c6], 32, 64));
    }
    if (lane < 16) {
        #pragma unroll
        for (int c6 = 0; c6 < 6; ++c6)
            s_red[wave * 96 + c6 * 16 + lane] = runmax[c6];
    }
    __syncthreads();
    if (tid < 96) {
        float m = fmaxf(fmaxf(s_red[tid], s_red[96 + tid]),
                        fmaxf(s_red[192 + tid], s_red[288 + tid]));
        feat[b * 192 + feat_off + tid] = fmaxf(m + bias[tid], 0.f);
    }
}

// ---------------------------------------------------------------------------
// LIGAND branch: round-2 kernel (proven; ~25 us).
// ---------------------------------------------------------------------------
__global__ __launch_bounds__(384) void conv_lig_kernel(
    const float* __restrict__ in,    // (B, 64, 100) f32
    const f16*   __restrict__ wp,    // (4, 96, 64) f16
    const float* __restrict__ bias,  // (96)
    float* __restrict__ feat,        // (B, 192)
    int feat_off)
{
    constexpr int V = 64, L = 100, KT = 4, VP = 64, KSTEPS = 4;
    constexpr int LP = 132, RS = 72, NTILES = 4, LOUT = 97;
    constexpr int RSB = RS * 2, NQ = V / 4;
    __shared__ __align__(16) char s_raw[LP * RSB];

    const int tid  = threadIdx.x;
    const int b    = blockIdx.x;
    const int wave = tid >> 6;
    const int lane = tid & 63;
    const int colw = wave % 3;
    const int roww = wave / 3;
    const int q    = lane >> 5;
    const int r    = lane & 31;

    {   // zero LDS (covers row pad)
        float4 z = {0.f, 0.f, 0.f, 0.f};
        float4* sz = (float4*)s_raw;
        for (int i = tid; i < LP * RSB / 16; i += 384) sz[i] = z;
    }
    __syncthreads();

    const float* gin = in + (size_t)b * (V * L);
    for (int i = tid; i < NQ * L; i += 384) {
        int q4 = i / L, p = i - q4 * L;
        const float* gp = gin + q4 * 4 * L + p;
        f16x4 hv = { (f16)gp[0], (f16)gp[L], (f16)gp[2 * L], (f16)gp[3 * L] };
        int off = (8 * q4) ^ (((p >> 3) & 3) << 4);
        *(f16x4*)(s_raw + p * RSB + off) = hv;
    }

    f16x8 bfr[KT][KSTEPS];
    #pragma unroll
    for (int t = 0; t < KT; ++t)
        #pragma unroll
        for (int ks = 0; ks < KSTEPS; ++ks)
            bfr[t][ks] = *(const f16x8*)(wp + (t * 96 + colw * 32 + r) * VP + ks * 16 + q * 8);

    __syncthreads();

    float runmax = -3.0e38f;
    for (int it = 0; it < NTILES / 2; ++it) {
        const int p0 = (roww * (NTILES / 2) + it) * 32;
        f32x16 acc = {};
        #pragma unroll
        for (int t = 0; t < KT; ++t) {
            int row = p0 + r + t;
            if (row > LP - 1) row = LP - 1;          // clamped row is zero
            const char* ap = s_raw + row * RSB;
            const int swz = ((row >> 3) & 3) << 4;
            #pragma unroll
            for (int ks = 0; ks < KSTEPS; ++ks) {
                f16x8 af = *(const f16x8*)(ap + ((ks * 32 + q * 16) ^ swz));
                acc = __builtin_amdgcn_mfma_f32_32x32x16_f16(af, bfr[t][ks], acc, 0, 0, 0);
            }
        }
        #pragma unroll
        for (int i = 0; i < 16; ++i) {
            int rr = (i & 3) + 8 * (i >> 2) + 4 * q;
            if (p0 + rr < LOUT) runmax = fmaxf(runmax, acc[i]);
        }
    }
    runmax = fmaxf(runmax, __shfl_xor(runmax, 32, 64));

    __syncthreads();
    float* s_red = (float*)s_raw;     // [2][96]
    if (lane < 32) s_red[roww * 96 + colw * 32 + r] = runmax;
    __syncthreads();
    if (tid < 96) {
        float m = fmaxf(s_red[tid], s_red[96 + tid]);
        feat[(size_t)b * 192 + feat_off + tid] = fmaxf(m + bias[tid], 0.f);
    }
}

// ---------------------------------------------------------------------------
// Gram + L2 normalize + readout (4 samples/block, one wave each).
// ---------------------------------------------------------------------------
__global__ __launch_bounds__(256) void gram_affinity_kernel(
    const float* __restrict__ feat, const float* __restrict__ w_aff,
    const float* __restrict__ b_aff, float* __restrict__ out, int B)
{
    const int lane = threadIdx.x & 63;
    const int wid  = threadIdx.x >> 6;
    const int b    = blockIdx.x * 4 + wid;

    __shared__ float s_x[4][192];

    if (b < B) {
        const float* fp = feat + (size_t)b * 192;
        for (int i = lane; i < 192; i += 64) s_x[wid][i] = fp[i];
    }
    __syncthreads();

    if (b < B) {
        float ssum = 0.f, sdot = 0.f;
        #pragma unroll
        for (int t = 0; t < 16; ++t) {
            const int jk = t * 64 + lane;
            const int j = jk >> 5, k = jk & 31;
            float gg = 0.f;
            #pragma unroll
            for (int i = 0; i < 6; ++i)
                gg = fmaf(s_x[wid][i * 32 + j], s_x[wid][i * 32 + k], gg);
            ssum = fmaf(gg, gg, ssum);
            sdot = fmaf(gg, w_aff[jk], sdot);
        }
        #pragma unroll
        for (int off = 32; off >= 1; off >>= 1) {
            ssum += __shfl_xor(ssum, off, 64);
            sdot += __shfl_xor(sdot, off, 64);
        }
        if (lane == 0) out[b] = sdot / (sqrtf(ssum) + 1e-12f) + b_aff[0];
    }
}

extern "C" void kernel_launch(void* const* d_in, const int* in_sizes, int n_in,
                              void* d_out, int out_size, void* d_ws, size_t ws_size,
                              hipStream_t stream)
{
    const float* protein = (const float*)d_in[0];  // (B, 25, 1000)
    const float* ligand  = (const float*)d_in[1];  // (B, 64, 100)
    const float* w_pro   = (const float*)d_in[2];  // (96, 25, 8)
    const float* b_pro   = (const float*)d_in[3];  // (96,)
    const float* w_lig   = (const float*)d_in[4];  // (96, 64, 4)
    const float* b_lig   = (const float*)d_in[5];  // (96,)
    const float* w_aff   = (const float*)d_in[6];  // (1024,)
    const float* b_aff   = (const float*)d_in[7];  // (1,)
    float* out = (float*)d_out;
    const int B = out_size;                        // 4096

    float* feat   = (float*)d_ws;                              // (B,192) f32
    f16*   wpackP = (f16*)((char*)d_ws + (size_t)B * 192 * 4); // 24576 f16
    f16*   wpackL = wpackP + 24576;                            // 4*96*64 f16

    repack_pro_kernel<<<96, 256, 0, stream>>>(w_pro, wpackP);
    repack_kernel<64, 4, 64><<<96, 256, 0, stream>>>(w_lig, wpackL);

    // ligand branch -> feat[:, 0:96]
    conv_lig_kernel<<<B, 384, 0, stream>>>(ligand, wpackL, b_lig, feat, 0);
    // protein branch -> feat[:, 96:192]
    conv_pro_kernel<<<B, 256, 0, stream>>>(protein, wpackP, b_pro, feat, 96);

    gram_affinity_kernel<<<(B + 3) / 4, 256, 0, stream>>>(feat, w_aff, b_aff, out, B);
}

// Round 14
// 301.003 us; speedup vs baseline: 1.3359x; 1.1932x over previous
//
#include <hip/hip_runtime.h>
#include <math.h>

typedef _Float16 f16;
typedef _Float16 f16x2 __attribute__((ext_vector_type(2)));
typedef _Float16 f16x4 __attribute__((ext_vector_type(4)));
typedef _Float16 f16x8 __attribute__((ext_vector_type(8)));
typedef float f32x4 __attribute__((ext_vector_type(4)));
typedef float f32x16 __attribute__((ext_vector_type(16)));

// ---------------------------------------------------------------------------
// Ligand repack: (96, V, K) fp32 -> wp[t][ch][VP] f16 (round-2 layout).
// ---------------------------------------------------------------------------
template<int V, int K, int VP>
__global__ void repack_kernel(const float* __restrict__ w, f16* __restrict__ wp) {
    int i = blockIdx.x * 256 + threadIdx.x;
    if (i >= K * 96 * VP) return;
    int v = i % VP, ch = (i / VP) % 96, t = i / (VP * 96);
    float val = (v < V) ? w[(ch * V + v) * K + t] : 0.f;
    wp[i] = (f16)val;
}

// ---------------------------------------------------------------------------
// Protein repack: CONFLICT-FREE B layout.
//   idx = ((t*6 + c6)*64 + lane)*8 + e, lane = g*16+r16, ch = c6*16+r16,
//   v = g*8+e. Lane l's 16B fragment at byte ((t*6+c6)*64+l)*16 ->
//   16-lane phases read 256B contiguous = 2 lanes/bank = free (m136).
// ---------------------------------------------------------------------------
__global__ void repack_pro_kernel(const float* __restrict__ w, f16* __restrict__ wp) {
    constexpr int V = 25, K = 8;
    int i = blockIdx.x * 256 + threadIdx.x;     // [0, 8*6*64*8)
    if (i >= K * 6 * 64 * 8) return;
    int e = i & 7, l = (i >> 3) & 63, c6 = (i >> 9) % 6, t = i / (512 * 6);
    int r16 = l & 15, g = l >> 4;
    int ch = c6 * 16 + r16, v = g * 8 + e;
    float val = (v < V) ? w[(ch * V + v) * K + t] : 0.f;
    wp[i] = (f16)val;
}

// ---------------------------------------------------------------------------
// PROTEIN. Round-10 kernel VERBATIM (proven 243us: LDS weights, CH=256,
// b32-pair staging, swz=((row>>3)&3)) with EXACTLY ONE change:
// B-fragment reads use the conflict-free [t][c6][lane] layout (r10's B-reads
// were 8-way conflicted; r13 verified the layout halves the conflict
// counter). Controlled A/B after r13 confounded two edits.
// ---------------------------------------------------------------------------
__global__ __launch_bounds__(256, 2) void conv_pro_kernel(
    const float* __restrict__ in,    // (B, 25, 1000) f32
    const f16*   __restrict__ wp,    // conflict-free layout, 49152 B
    const float* __restrict__ bias,  // (96)
    float* __restrict__ feat,        // (B, 192)
    int feat_off)
{
    constexpr int V = 25, L = 1000, KT = 8, LOUT = 993;
    constexpr int CH  = 256;          // output rows per chunk
    constexpr int NC  = 4;            // chunks
    constexpr int BR  = 264;          // buffer rows (256 + 7 halo, pad 264)
    constexpr int RSB = 80;           // row stride bytes (64 payload + 16 pad)
    constexpr int P4  = BR / 4;       // 66 p-quads per buffer
    constexpr int NVP = 13;           // vocab pairs (v24 pairs with zero v25)
    constexpr int NU  = NVP * P4;     // 858 staging units
    constexpr int NW  = KT * 6 * 64 * 8;  // 24576 f16 (49152 B)

    __shared__ __align__(16) char s_raw[BR * RSB];   // 21.1 KB input buffer
    __shared__ __align__(16) f16  s_w[NW];           // 49.2 KB weights
    __shared__ float s_red[4 * 96];

    const int tid  = threadIdx.x;
    const int wave = tid >> 6;
    const int lane = tid & 63;
    const int g    = lane >> 4;       // k-oct (0..3)
    const int r16  = lane & 15;       // A-row / B-col within 16-tile
    const size_t b = blockIdx.x;
    const float* gs = in + b * (size_t)(V * L);

    // ---- one-time: weights -> LDS (linear f16x8 copy, coalesced) ----
    {
        const f16x8* wg = (const f16x8*)wp;
        f16x8* wl = (f16x8*)s_w;
        #pragma unroll
        for (int u = 0; u < NW / 8 / 256; ++u)       // 12 iters
            wl[u * 256 + tid] = wg[u * 256 + tid];
    }
    // ---- one-time: zero v-pad slot (payload bytes 48..63) of every row;
    // staging rewrites bytes 48..51 (v24,v25) each chunk, v26..31 stay 0.
    for (int row = tid; row < BR; row += 256) {
        const int swz = ((row >> 3) & 3) << 4;
        *(f16x8*)(s_raw + row * RSB + (48 ^ swz)) = (f16x8){};
    }
    __syncthreads();

    float runmax[6];
    #pragma unroll
    for (int c6 = 0; c6 < 6; ++c6) runmax[c6] = -3.0e38f;

    for (int c = 0; c < NC; ++c) {
        if (c) __syncthreads();       // previous chunk's compute done
        // ---- stage chunk c: unit = (vocab-pair, p-quad), b32 LDS writes ----
        #pragma unroll
        for (int u = 0; u < 4; ++u) {
            const int i = u * 256 + tid;
            if (i < NU) {
                const int v2 = i / P4, p4 = i - v2 * P4;
                const int p  = 4 * p4;
                const int gp = c * CH + p;
                float4 x0 = {0.f, 0.f, 0.f, 0.f}, x1 = {0.f, 0.f, 0.f, 0.f};
                if (gp < L) {
                    x0 = *(const float4*)(gs + (size_t)(2 * v2) * L + gp);
                    if (2 * v2 + 1 < V)
                        x1 = *(const float4*)(gs + (size_t)(2 * v2 + 1) * L + gp);
                }
                const int pb = 4 * v2;                 // payload byte offset
                const int slot = pb & 48, sub = pb & 12;
                const float vx0[4] = {x0.x, x0.y, x0.z, x0.w};
                const float vx1[4] = {x1.x, x1.y, x1.z, x1.w};
                #pragma unroll
                for (int j = 0; j < 4; ++j) {
                    const int row = p + j;
                    const int swz = ((row >> 3) & 3) << 4;
                    f16x2 hv = { (f16)vx0[j], (f16)vx1[j] };
                    *(f16x2*)(s_raw + row * RSB + ((slot ^ swz) + sub)) = hv;
                }
            }
        }
        __syncthreads();              // staging visible

        // ---- compute: wave owns rows [wave*64, wave*64+63] (4 row-tiles) ----
        f32x4 acc[4][6] = {};
        #pragma unroll 1
        for (int t = 0; t < KT; ++t) {
            f16x8 bf[6];
            #pragma unroll
            for (int c6 = 0; c6 < 6; ++c6)
                bf[c6] = *(const f16x8*)(s_w + ((t * 6 + c6) * 64 + lane) * 8);
            #pragma unroll
            for (int rt = 0; rt < 4; ++rt) {
                const int row = wave * 64 + rt * 16 + r16 + t;   // <= 262 < BR
                const int swz = ((row >> 3) & 3) << 4;
                f16x8 a = *(const f16x8*)(s_raw + row * RSB + ((g * 16) ^ swz));
                #pragma unroll
                for (int c6 = 0; c6 < 6; ++c6)
                    acc[rt][c6] = __builtin_amdgcn_mfma_f32_16x16x32_f16(a, bf[c6], acc[rt][c6], 0, 0, 0);
            }
        }
        // ---- fold acc into runmax; C/D: col=lane&15, row=g*4+i ----
        #pragma unroll
        for (int rt = 0; rt < 4; ++rt) {
            const int pt = c * CH + wave * 64 + rt * 16;
            if (pt + 16 <= LOUT) {
                #pragma unroll
                for (int c6 = 0; c6 < 6; ++c6)
                    #pragma unroll
                    for (int i = 0; i < 4; ++i)
                        runmax[c6] = fmaxf(runmax[c6], acc[rt][c6][i]);
            } else {
                const int p0g = pt + g * 4;
                #pragma unroll
                for (int c6 = 0; c6 < 6; ++c6)
                    #pragma unroll
                    for (int i = 0; i < 4; ++i)
                        if (p0g + i < LOUT) runmax[c6] = fmaxf(runmax[c6], acc[rt][c6][i]);
            }
        }
    }

    // ---- reduce: channel c6*16+r16 held by g-groups {r16, +16, +32, +48} ----
    #pragma unroll
    for (int c6 = 0; c6 < 6; ++c6) {
        runmax[c6] = fmaxf(runmax[c6], __shfl_xor(runmax[c6], 16, 64));
        runmax[c6] = fmaxf(runmax[c6], __shfl_xor(runmax[c6], 32, 64));
    }
    if (lane < 16) {
        #pragma unroll
        for (int c6 = 0; c6 < 6; ++c6)
            s_red[wave * 96 + c6 * 16 + lane] = runmax[c6];
    }
    __syncthreads();
    if (tid < 96) {
        float m = fmaxf(fmaxf(s_red[tid], s_red[96 + tid]),
                        fmaxf(s_red[192 + tid], s_red[288 + tid]));
        feat[b * 192 + feat_off + tid] = fmaxf(m + bias[tid], 0.f);
    }
}

// ---------------------------------------------------------------------------
// LIGAND branch: round-2 kernel (proven; ~25 us).
// ---------------------------------------------------------------------------
__global__ __launch_bounds__(384) void conv_lig_kernel(
    const float* __restrict__ in,    // (B, 64, 100) f32
    const f16*   __restrict__ wp,    // (4, 96, 64) f16
    const float* __restrict__ bias,  // (96)
    float* __restrict__ feat,        // (B, 192)
    int feat_off)
{
    constexpr int V = 64, L = 100, KT = 4, VP = 64, KSTEPS = 4;
    constexpr int LP = 132, RS = 72, NTILES = 4, LOUT = 97;
    constexpr int RSB = RS * 2, NQ = V / 4;
    __shared__ __align__(16) char s_raw[LP * RSB];

    const int tid  = threadIdx.x;
    const int b    = blockIdx.x;
    const int wave = tid >> 6;
    const int lane = tid & 63;
    const int colw = wave % 3;
    const int roww = wave / 3;
    const int q    = lane >> 5;
    const int r    = lane & 31;

    {   // zero LDS (covers row pad)
        float4 z = {0.f, 0.f, 0.f, 0.f};
        float4* sz = (float4*)s_raw;
        for (int i = tid; i < LP * RSB / 16; i += 384) sz[i] = z;
    }
    __syncthreads();

    const float* gin = in + (size_t)b * (V * L);
    for (int i = tid; i < NQ * L; i += 384) {
        int q4 = i / L, p = i - q4 * L;
        const float* gp = gin + q4 * 4 * L + p;
        f16x4 hv = { (f16)gp[0], (f16)gp[L], (f16)gp[2 * L], (f16)gp[3 * L] };
        int off = (8 * q4) ^ (((p >> 3) & 3) << 4);
        *(f16x4*)(s_raw + p * RSB + off) = hv;
    }

    f16x8 bfr[KT][KSTEPS];
    #pragma unroll
    for (int t = 0; t < KT; ++t)
        #pragma unroll
        for (int ks = 0; ks < KSTEPS; ++ks)
            bfr[t][ks] = *(const f16x8*)(wp + (t * 96 + colw * 32 + r) * VP + ks * 16 + q * 8);

    __syncthreads();

    float runmax = -3.0e38f;
    for (int it = 0; it < NTILES / 2; ++it) {
        const int p0 = (roww * (NTILES / 2) + it) * 32;
        f32x16 acc = {};
        #pragma unroll
        for (int t = 0; t < KT; ++t) {
            int row = p0 + r + t;
            if (row > LP - 1) row = LP - 1;          // clamped row is zero
            const char* ap = s_raw + row * RSB;
            const int swz = ((row >> 3) & 3) << 4;
            #pragma unroll
            for (int ks = 0; ks < KSTEPS; ++ks) {
                f16x8 af = *(const f16x8*)(ap + ((ks * 32 + q * 16) ^ swz));
                acc = __builtin_amdgcn_mfma_f32_32x32x16_f16(af, bfr[t][ks], acc, 0, 0, 0);
            }
        }
        #pragma unroll
        for (int i = 0; i < 16; ++i) {
            int rr = (i & 3) + 8 * (i >> 2) + 4 * q;
            if (p0 + rr < LOUT) runmax = fmaxf(runmax, acc[i]);
        }
    }
    runmax = fmaxf(runmax, __shfl_xor(runmax, 32, 64));

    __syncthreads();
    float* s_red = (float*)s_raw;     // [2][96]
    if (lane < 32) s_red[roww * 96 + colw * 32 + r] = runmax;
    __syncthreads();
    if (tid < 96) {
        float m = fmaxf(s_red[tid], s_red[96 + tid]);
        feat[(size_t)b * 192 + feat_off + tid] = fmaxf(m + bias[tid], 0.f);
    }
}

// ---------------------------------------------------------------------------
// Gram + L2 normalize + readout (4 samples/block, one wave each).
// ---------------------------------------------------------------------------
__global__ __launch_bounds__(256) void gram_affinity_kernel(
    const float* __restrict__ feat, const float* __restrict__ w_aff,
    const float* __restrict__ b_aff, float* __restrict__ out, int B)
{
    const int lane = threadIdx.x & 63;
    const int wid  = threadIdx.x >> 6;
    const int b    = blockIdx.x * 4 + wid;

    __shared__ float s_x[4][192];

    if (b < B) {
        const float* fp = feat + (size_t)b * 192;
        for (int i = lane; i < 192; i += 64) s_x[wid][i] = fp[i];
    }
    __syncthreads();

    if (b < B) {
        float ssum = 0.f, sdot = 0.f;
        #pragma unroll
        for (int t = 0; t < 16; ++t) {
            const int jk = t * 64 + lane;
            const int j = jk >> 5, k = jk & 31;
            float gg = 0.f;
            #pragma unroll
            for (int i = 0; i < 6; ++i)
                gg = fmaf(s_x[wid][i * 32 + j], s_x[wid][i * 32 + k], gg);
            ssum = fmaf(gg, gg, ssum);
            sdot = fmaf(gg, w_aff[jk], sdot);
        }
        #pragma unroll
        for (int off = 32; off >= 1; off >>= 1) {
            ssum += __shfl_xor(ssum, off, 64);
            sdot += __shfl_xor(sdot, off, 64);
        }
        if (lane == 0) out[b] = sdot / (sqrtf(ssum) + 1e-12f) + b_aff[0];
    }
}

extern "C" void kernel_launch(void* const* d_in, const int* in_sizes, int n_in,
                              void* d_out, int out_size, void* d_ws, size_t ws_size,
                              hipStream_t stream)
{
    const float* protein = (const float*)d_in[0];  // (B, 25, 1000)
    const float* ligand  = (const float*)d_in[1];  // (B, 64, 100)
    const float* w_pro   = (const float*)d_in[2];  // (96, 25, 8)
    const float* b_pro   = (const float*)d_in[3];  // (96,)
    const float* w_lig   = (const float*)d_in[4];  // (96, 64, 4)
    const float* b_lig   = (const float*)d_in[5];  // (96,)
    const float* w_aff   = (const float*)d_in[6];  // (1024,)
    const float* b_aff   = (const float*)d_in[7];  // (1,)
    float* out = (float*)d_out;
    const int B = out_size;                        // 4096

    float* feat   = (float*)d_ws;                              // (B,192) f32
    f16*   wpackP = (f16*)((char*)d_ws + (size_t)B * 192 * 4); // 24576 f16
    f16*   wpackL = wpackP + 24576;                            // 4*96*64 f16

    repack_pro_kernel<<<96, 256, 0, stream>>>(w_pro, wpackP);
    repack_kernel<64, 4, 64><<<96, 256, 0, stream>>>(w_lig, wpackL);

    // ligand branch -> feat[:, 0:96]
    conv_lig_kernel<<<B, 384, 0, stream>>>(ligand, wpackL, b_lig, feat, 0);
    // protein branch -> feat[:, 96:192]
    conv_pro_kernel<<<B, 256, 0, stream>>>(protein, wpackP, b_pro, feat, 96);

    gram_affinity_kernel<<<(B + 3) / 4, 256, 0, stream>>>(feat, w_aff, b_aff, out, B);
}

// Round 15
// 283.690 us; speedup vs baseline: 1.4174x; 1.0610x over previous
//
#include <hip/hip_runtime.h>
#include <math.h>

typedef _Float16 f16;
typedef _Float16 f16x2 __attribute__((ext_vector_type(2)));
typedef _Float16 f16x4 __attribute__((ext_vector_type(4)));
typedef _Float16 f16x8 __attribute__((ext_vector_type(8)));
typedef float f32x4 __attribute__((ext_vector_type(4)));
typedef float f32x16 __attribute__((ext_vector_type(16)));

// ---------------------------------------------------------------------------
// Ligand repack: (96, V, K) fp32 -> wp[t][ch][VP] f16 (round-2 layout).
// ---------------------------------------------------------------------------
template<int V, int K, int VP>
__global__ void repack_kernel(const float* __restrict__ w, f16* __restrict__ wp) {
    int i = blockIdx.x * 256 + threadIdx.x;
    if (i >= K * 96 * VP) return;
    int v = i % VP, ch = (i / VP) % 96, t = i / (VP * 96);
    float val = (v < V) ? w[(ch * V + v) * K + t] : 0.f;
    wp[i] = (f16)val;
}

// ---------------------------------------------------------------------------
// Protein repack: CONFLICT-FREE B layout (r14, proven).
//   idx = ((t*6 + c6)*64 + lane)*8 + e, lane = g*16+r16, ch = c6*16+r16,
//   v = g*8+e.
// ---------------------------------------------------------------------------
__global__ void repack_pro_kernel(const float* __restrict__ w, f16* __restrict__ wp) {
    constexpr int V = 25, K = 8;
    int i = blockIdx.x * 256 + threadIdx.x;     // [0, 8*6*64*8)
    if (i >= K * 6 * 64 * 8) return;
    int e = i & 7, l = (i >> 3) & 63, c6 = (i >> 9) % 6, t = i / (512 * 6);
    int r16 = l & 15, g = l >> 4;
    int ch = c6 * 16 + r16, v = g * 8 + e;
    float val = (v < V) ? w[(ch * V + v) * K + t] : 0.f;
    wp[i] = (f16)val;
}

// ---------------------------------------------------------------------------
// PROTEIN. r14 kernel with ONE change: 512 threads (8 waves) per block.
// r14's A/B proved conflicts are latency-absorbed -> structure is
// latency/serialization-bound at 8 waves/CU. 512 thr keeps LDS (73.3 KB,
// 2 blocks/CU) but doubles TLP to 16 waves/CU (4/SIMD): stage-phase serial
// load chain halves (1.7 float4/thread), compute DS latency better covered.
// acc[2][6]=48 VGPR -> fits 128-reg tier for 4 waves/SIMD.
// ---------------------------------------------------------------------------
__global__ __launch_bounds__(512, 4) void conv_pro_kernel(
    const float* __restrict__ in,    // (B, 25, 1000) f32
    const f16*   __restrict__ wp,    // conflict-free layout, 49152 B
    const float* __restrict__ bias,  // (96)
    float* __restrict__ feat,        // (B, 192)
    int feat_off)
{
    constexpr int V = 25, L = 1000, KT = 8, LOUT = 993;
    constexpr int CH  = 256;          // output rows per chunk
    constexpr int NC  = 4;            // chunks
    constexpr int BR  = 264;          // buffer rows (256 + 7 halo, pad 264)
    constexpr int RSB = 80;           // row stride bytes (64 payload + 16 pad)
    constexpr int P4  = BR / 4;       // 66 p-quads per buffer
    constexpr int NVP = 13;           // vocab pairs (v24 pairs with zero v25)
    constexpr int NU  = NVP * P4;     // 858 staging units
    constexpr int NW  = KT * 6 * 64 * 8;  // 24576 f16 (49152 B)

    __shared__ __align__(16) char s_raw[BR * RSB];   // 21.1 KB input buffer
    __shared__ __align__(16) f16  s_w[NW];           // 49.2 KB weights
    __shared__ float s_red[8 * 96];                  // 3 KB

    const int tid  = threadIdx.x;
    const int wave = tid >> 6;        // 0..7
    const int lane = tid & 63;
    const int g    = lane >> 4;       // k-oct (0..3)
    const int r16  = lane & 15;       // A-row / B-col within 16-tile
    const size_t b = blockIdx.x;
    const float* gs = in + b * (size_t)(V * L);

    // ---- one-time: weights -> LDS (linear f16x8 copy, coalesced) ----
    {
        const f16x8* wg = (const f16x8*)wp;
        f16x8* wl = (f16x8*)s_w;
        #pragma unroll
        for (int u = 0; u < NW / 8 / 512; ++u)       // 6 iters
            wl[u * 512 + tid] = wg[u * 512 + tid];
    }
    // ---- one-time: zero v-pad slot (payload bytes 48..63) of every row ----
    for (int row = tid; row < BR; row += 512) {
        const int swz = ((row >> 3) & 3) << 4;
        *(f16x8*)(s_raw + row * RSB + (48 ^ swz)) = (f16x8){};
    }
    __syncthreads();

    float runmax[6];
    #pragma unroll
    for (int c6 = 0; c6 < 6; ++c6) runmax[c6] = -3.0e38f;

    for (int c = 0; c < NC; ++c) {
        if (c) __syncthreads();       // previous chunk's compute done
        // ---- stage chunk c: unit = (vocab-pair, p-quad), b32 LDS writes ----
        #pragma unroll
        for (int u = 0; u < 2; ++u) {
            const int i = u * 512 + tid;
            if (i < NU) {
                const int v2 = i / P4, p4 = i - v2 * P4;
                const int p  = 4 * p4;
                const int gp = c * CH + p;
                float4 x0 = {0.f, 0.f, 0.f, 0.f}, x1 = {0.f, 0.f, 0.f, 0.f};
                if (gp < L) {
                    x0 = *(const float4*)(gs + (size_t)(2 * v2) * L + gp);
                    if (2 * v2 + 1 < V)
                        x1 = *(const float4*)(gs + (size_t)(2 * v2 + 1) * L + gp);
                }
                const int pb = 4 * v2;                 // payload byte offset
                const int slot = pb & 48, sub = pb & 12;
                const float vx0[4] = {x0.x, x0.y, x0.z, x0.w};
                const float vx1[4] = {x1.x, x1.y, x1.z, x1.w};
                #pragma unroll
                for (int j = 0; j < 4; ++j) {
                    const int row = p + j;
                    const int swz = ((row >> 3) & 3) << 4;
                    f16x2 hv = { (f16)vx0[j], (f16)vx1[j] };
                    *(f16x2*)(s_raw + row * RSB + ((slot ^ swz) + sub)) = hv;
                }
            }
        }
        __syncthreads();              // staging visible

        // ---- compute: wave owns rows [wave*32, wave*32+31] (2 row-tiles) ----
        f32x4 acc[2][6] = {};
        #pragma unroll 1
        for (int t = 0; t < KT; ++t) {
            f16x8 bf[6];
            #pragma unroll
            for (int c6 = 0; c6 < 6; ++c6)
                bf[c6] = *(const f16x8*)(s_w + ((t * 6 + c6) * 64 + lane) * 8);
            #pragma unroll
            for (int rt = 0; rt < 2; ++rt) {
                const int row = wave * 32 + rt * 16 + r16 + t;   // <= 262 < BR
                const int swz = ((row >> 3) & 3) << 4;
                f16x8 a = *(const f16x8*)(s_raw + row * RSB + ((g * 16) ^ swz));
                #pragma unroll
                for (int c6 = 0; c6 < 6; ++c6)
                    acc[rt][c6] = __builtin_amdgcn_mfma_f32_16x16x32_f16(a, bf[c6], acc[rt][c6], 0, 0, 0);
            }
        }
        // ---- fold acc into runmax; C/D: col=lane&15, row=g*4+i ----
        #pragma unroll
        for (int rt = 0; rt < 2; ++rt) {
            const int pt = c * CH + wave * 32 + rt * 16;
            if (pt + 16 <= LOUT) {
                #pragma unroll
                for (int c6 = 0; c6 < 6; ++c6)
                    #pragma unroll
                    for (int i = 0; i < 4; ++i)
                        runmax[c6] = fmaxf(runmax[c6], acc[rt][c6][i]);
            } else {
                const int p0g = pt + g * 4;
                #pragma unroll
                for (int c6 = 0; c6 < 6; ++c6)
                    #pragma unroll
                    for (int i = 0; i < 4; ++i)
                        if (p0g + i < LOUT) runmax[c6] = fmaxf(runmax[c6], acc[rt][c6][i]);
            }
        }
    }

    // ---- reduce: channel c6*16+r16 held by g-groups {r16, +16, +32, +48} ----
    #pragma unroll
    for (int c6 = 0; c6 < 6; ++c6) {
        runmax[c6] = fmaxf(runmax[c6], __shfl_xor(runmax[c6], 16, 64));
        runmax[c6] = fmaxf(runmax[c6], __shfl_xor(runmax[c6], 32, 64));
    }
    if (lane < 16) {
        #pragma unroll
        for (int c6 = 0; c6 < 6; ++c6)
            s_red[wave * 96 + c6 * 16 + lane] = runmax[c6];
    }
    __syncthreads();
    if (tid < 96) {
        float m = s_red[tid];
        #pragma unroll
        for (int w = 1; w < 8; ++w) m = fmaxf(m, s_red[w * 96 + tid]);
        feat[b * 192 + feat_off + tid] = fmaxf(m + bias[tid], 0.f);
    }
}

// ---------------------------------------------------------------------------
// LIGAND branch: round-2 kernel (proven; ~25 us).
// ---------------------------------------------------------------------------
__global__ __launch_bounds__(384) void conv_lig_kernel(
    const float* __restrict__ in,    // (B, 64, 100) f32
    const f16*   __restrict__ wp,    // (4, 96, 64) f16
    const float* __restrict__ bias,  // (96)
    float* __restrict__ feat,        // (B, 192)
    int feat_off)
{
    constexpr int V = 64, L = 100, KT = 4, VP = 64, KSTEPS = 4;
    constexpr int LP = 132, RS = 72, NTILES = 4, LOUT = 97;
    constexpr int RSB = RS * 2, NQ = V / 4;
    __shared__ __align__(16) char s_raw[LP * RSB];

    const int tid  = threadIdx.x;
    const int b    = blockIdx.x;
    const int wave = tid >> 6;
    const int lane = tid & 63;
    const int colw = wave % 3;
    const int roww = wave / 3;
    const int q    = lane >> 5;
    const int r    = lane & 31;

    {   // zero LDS (covers row pad)
        float4 z = {0.f, 0.f, 0.f, 0.f};
        float4* sz = (float4*)s_raw;
        for (int i = tid; i < LP * RSB / 16; i += 384) sz[i] = z;
    }
    __syncthreads();

    const float* gin = in + (size_t)b * (V * L);
    for (int i = tid; i < NQ * L; i += 384) {
        int q4 = i / L, p = i - q4 * L;
        const float* gp = gin + q4 * 4 * L + p;
        f16x4 hv = { (f16)gp[0], (f16)gp[L], (f16)gp[2 * L], (f16)gp[3 * L] };
        int off = (8 * q4) ^ (((p >> 3) & 3) << 4);
        *(f16x4*)(s_raw + p * RSB + off) = hv;
    }

    f16x8 bfr[KT][KSTEPS];
    #pragma unroll
    for (int t = 0; t < KT; ++t)
        #pragma unroll
        for (int ks = 0; ks < KSTEPS; ++ks)
            bfr[t][ks] = *(const f16x8*)(wp + (t * 96 + colw * 32 + r) * VP + ks * 16 + q * 8);

    __syncthreads();

    float runmax = -3.0e38f;
    for (int it = 0; it < NTILES / 2; ++it) {
        const int p0 = (roww * (NTILES / 2) + it) * 32;
        f32x16 acc = {};
        #pragma unroll
        for (int t = 0; t < KT; ++t) {
            int row = p0 + r + t;
            if (row > LP - 1) row = LP - 1;          // clamped row is zero
            const char* ap = s_raw + row * RSB;
            const int swz = ((row >> 3) & 3) << 4;
            #pragma unroll
            for (int ks = 0; ks < KSTEPS; ++ks) {
                f16x8 af = *(const f16x8*)(ap + ((ks * 32 + q * 16) ^ swz));
                acc = __builtin_amdgcn_mfma_f32_32x32x16_f16(af, bfr[t][ks], acc, 0, 0, 0);
            }
        }
        #pragma unroll
        for (int i = 0; i < 16; ++i) {
            int rr = (i & 3) + 8 * (i >> 2) + 4 * q;
            if (p0 + rr < LOUT) runmax = fmaxf(runmax, acc[i]);
        }
    }
    runmax = fmaxf(runmax, __shfl_xor(runmax, 32, 64));

    __syncthreads();
    float* s_red = (float*)s_raw;     // [2][96]
    if (lane < 32) s_red[roww * 96 + colw * 32 + r] = runmax;
    __syncthreads();
    if (tid < 96) {
        float m = fmaxf(s_red[tid], s_red[96 + tid]);
        feat[(size_t)b * 192 + feat_off + tid] = fmaxf(m + bias[tid], 0.f);
    }
}

// ---------------------------------------------------------------------------
// Gram + L2 normalize + readout (4 samples/block, one wave each).
// ---------------------------------------------------------------------------
__global__ __launch_bounds__(256) void gram_affinity_kernel(
    const float* __restrict__ feat, const float* __restrict__ w_aff,
    const float* __restrict__ b_aff, float* __restrict__ out, int B)
{
    const int lane = threadIdx.x & 63;
    const int wid  = threadIdx.x >> 6;
    const int b    = blockIdx.x * 4 + wid;

    __shared__ float s_x[4][192];

    if (b < B) {
        const float* fp = feat + (size_t)b * 192;
        for (int i = lane; i < 192; i += 64) s_x[wid][i] = fp[i];
    }
    __syncthreads();

    if (b < B) {
        float ssum = 0.f, sdot = 0.f;
        #pragma unroll
        for (int t = 0; t < 16; ++t) {
            const int jk = t * 64 + lane;
            const int j = jk >> 5, k = jk & 31;
            float gg = 0.f;
            #pragma unroll
            for (int i = 0; i < 6; ++i)
                gg = fmaf(s_x[wid][i * 32 + j], s_x[wid][i * 32 + k], gg);
            ssum = fmaf(gg, gg, ssum);
            sdot = fmaf(gg, w_aff[jk], sdot);
        }
        #pragma unroll
        for (int off = 32; off >= 1; off >>= 1) {
            ssum += __shfl_xor(ssum, off, 64);
            sdot += __shfl_xor(sdot, off, 64);
        }
        if (lane == 0) out[b] = sdot / (sqrtf(ssum) + 1e-12f) + b_aff[0];
    }
}

extern "C" void kernel_launch(void* const* d_in, const int* in_sizes, int n_in,
                              void* d_out, int out_size, void* d_ws, size_t ws_size,
                              hipStream_t stream)
{
    const float* protein = (const float*)d_in[0];  // (B, 25, 1000)
    const float* ligand  = (const float*)d_in[1];  // (B, 64, 100)
    const float* w_pro   = (const float*)d_in[2];  // (96, 25, 8)
    const float* b_pro   = (const float*)d_in[3];  // (96,)
    const float* w_lig   = (const float*)d_in[4];  // (96, 64, 4)
    const float* b_lig   = (const float*)d_in[5];  // (96,)
    const float* w_aff   = (const float*)d_in[6];  // (1024,)
    const float* b_aff   = (const float*)d_in[7];  // (1,)
    float* out = (float*)d_out;
    const int B = out_size;                        // 4096

    float* feat   = (float*)d_ws;                              // (B,192) f32
    f16*   wpackP = (f16*)((char*)d_ws + (size_t)B * 192 * 4); // 24576 f16
    f16*   wpackL = wpackP + 24576;                            // 4*96*64 f16

    repack_pro_kernel<<<96, 256, 0, stream>>>(w_pro, wpackP);
    repack_kernel<64, 4, 64><<<96, 256, 0, stream>>>(w_lig, wpackL);

    // ligand branch -> feat[:, 0:96]
    conv_lig_kernel<<<B, 384, 0, stream>>>(ligand, wpackL, b_lig, feat, 0);
    // protein branch -> feat[:, 96:192]
    conv_pro_kernel<<<B, 512, 0, stream>>>(protein, wpackP, b_pro, feat, 96);

    gram_affinity_kernel<<<(B + 3) / 4, 256, 0, stream>>>(feat, w_aff, b_aff, out, B);
}